// Round 3
// baseline (435.269 us; speedup 1.0000x reference)
//
#include <hip/hip_runtime.h>

// LSTMPricePredictor: B=4096, T=512, IN=1, H=50, 2 layers + FC(50->1)
// R19 = R17 (13-wave, best 362us) + two-barrier K-split pipeline.
//   Post-mortem R18: halving LDS reads (7 waves x 2 tiles) REGRESSED ->
//   step time is a SUM of lockstep phase bursts (read ~600, MFMA ~100,
//   EW-trans ~500, write+bar ~200), not pipe-throughput-capped.
//   R19 overlaps the bursts: step split at MFMA-K granularity.
//     phase0: all waves read chunk0 (cells 0..31) + 3 MFMAs; group B
//             (waves 8..12, cells 32..51) runs its DEFERRED EW + writes
//             chunk1 h-data (trans pipe || LDS/MFMA pipes).
//     bar2 gates B's writes -> phase1: read chunk1 + 3 MFMAs; group A
//             (waves 0..7) EW + writes chunk0 h-data; B defers acc in regs.
//     bar1 gates A's writes -> next step.
//   Hazards: every buffer region's previous reader is >=2 barriers back
//   (double buffers unchanged). Trans floor ~364 cyc/SIMD/step invariant.
// Carried from R17: x rank-1 via LDS stage, bias as MFMA C-operand,
//   unconditional h stores into dead k=50/51 slots, 2-rcp cell_update
//   with c pre-scaled by 2*log2e, raw v_exp_f32.

typedef _Float16 half8 __attribute__((ext_vector_type(8)));
typedef float    f32x4 __attribute__((ext_vector_type(4)));

#define TT    512
#define HID   50
#define NB    16         // batch rows per block
#define XST   17         // xs row stride in floats (bank-conflict-free)
#define LOG2E 1.44269504f

// Weight A-fragment: lane's 8 fp16 for K-chunk `chunk`, pre-scaled by the
// gate's exp2 factor. Row m -> gate = m&3, cell = 4*wv + (m>>2).
// W is (200 x 50): element [gate*50+cell][k]. Rows with cell >= 50 and
// k-slots >= 50 are zero (dead lanes multiply by zero).
__device__ __forceinline__ float4 make_wfrag(const float* W, int gate, int cell,
                                             int chunk, int quad, float scale) {
    half8 hv = {};
    #pragma unroll
    for (int j = 0; j < 8; ++j) {
        const int k = 32 * chunk + 8 * quad + j;
        float v = 0.0f;
        if (cell < HID && k < HID) v = W[(gate * HID + cell) * HID + k] * scale;
        hv[j] = (_Float16)v;
    }
    return __builtin_bit_cast(float4, hv);
}

// Shared-rcp LSTM cell update on pre-scaled gates, RAW hardware exp2.
//   a0 = -i*log2e, a1 = -f*log2e, a2 = 2g*log2e, a3 = -o*log2e.
// ct = c * 2*log2e carried across steps. Common denominator:
//   ct' = [ct*p + K(eg-1)*q] / (p*q),  p=(1+ei)(1+eg), q=(1+ef), K=2log2e.
// Worst-case p*q <= 2^82 -- no overflow. Dead lanes: all-zero gates give
// ei=ef=eg=eo=1 -> ct stays 0, h = 0 exactly.
__device__ __forceinline__ float cell_update(const f32x4 a, float& ct) {
    const float K  = 2.0f * LOG2E;
    const float ei = __builtin_amdgcn_exp2f(a[0]);   // e^{-i}
    const float ef = __builtin_amdgcn_exp2f(a[1]);   // e^{-f}
    const float eg = __builtin_amdgcn_exp2f(a[2]);   // e^{2g}
    const float eo = __builtin_amdgcn_exp2f(a[3]);   // e^{-o}
    const float p  = (1.0f + ei) * (1.0f + eg);
    const float q  = 1.0f + ef;
    const float t1 = __builtin_fmaf(eg, K, -K);                  // K*(eg-1)
    const float num = __builtin_fmaf(ct, p, t1 * q);
    ct = num * __builtin_amdgcn_rcpf(p * q);                     // K*c'
    const float ec = __builtin_amdgcn_exp2f(ct);                 // e^{2c'}
    return (ec - 1.0f) *
        __builtin_amdgcn_rcpf((1.0f + eo) * (ec + 1.0f));        // sig(o)*tanh(c')
}

#define PIN(f) asm volatile("" : "+v"(f.x), "+v"(f.y), "+v"(f.z), "+v"(f.w));
#define MFMA(af, b, c) __builtin_amdgcn_mfma_f32_16x16x32_f16(__builtin_bit_cast(half8, (af)), (b), (c), 0, 0, 0)

extern "C" __global__ __launch_bounds__(832, 4)
void lstm2_mfma_kernel(const float* __restrict__ x,
                       const float* __restrict__ W_ih0, const float* __restrict__ W_hh0,
                       const float* __restrict__ b_ih0, const float* __restrict__ b_hh0,
                       const float* __restrict__ W_ih1, const float* __restrict__ W_hh1,
                       const float* __restrict__ b_ih1, const float* __restrict__ b_hh1,
                       const float* __restrict__ fc_w, const float* __restrict__ fc_b,
                       float* __restrict__ out)
{
    // h-state in B-fragment layout: element (k, n) at (k>>5)*512 +
    // (((k&31)>>3)*16 + n)*8 + (k&7). k<50 = h; k=50/51 slots are dead
    // (zero A-weights) and absorb the cellD=50/51 stores (h=0 anyway).
    __shared__ _Float16 H0[2][1024];
    __shared__ _Float16 H1[2][1024];
    __shared__ float    xs[TT * XST];     // x staged fp32, [u*XST + col]
    __shared__ float    hfin[52 * NB];    // fp32 h1^(TT) for the FC epilogue

    const int tid  = threadIdx.x;
    const int lane = tid & 63;
    const int wv   = tid >> 6;            // wave 0..12 = gate-row tile
    const int b0   = blockIdx.x * NB;

    for (int i = tid; i < 1024; i += 832) {
        H0[0][i] = (_Float16)0.f; H0[1][i] = (_Float16)0.f;
        H1[0][i] = (_Float16)0.f; H1[1][i] = (_Float16)0.f;
    }
    // One-shot x stage: coalesced global read, stride-17 LDS write.
    for (int i = tid; i < NB * TT; i += 832) {
        const int row = i >> 9;           // batch row 0..15
        const int uu  = i & (TT - 1);     // timestep
        xs[uu * XST + row] = x[(size_t)(b0 + row) * TT + uu];
    }

    const int quad = lane >> 4;
    const int col  = lane & 15;           // batch column
    const int mrow = lane & 15;           // A-row within tile
    const int gateA = mrow & 3;
    const int cellA = 4 * wv + (mrow >> 2);
    const float scA = (gateA == 2) ? 2.0f * LOG2E : -LOG2E;

    // ---- A-fragments (weights, exp2-prescaled), loaded once, pinned ----
    float4 A0c0 = make_wfrag(W_hh0, gateA, cellA, 0, quad, scA);
    float4 A0c1 = make_wfrag(W_hh0, gateA, cellA, 1, quad, scA);
    float4 Aic0 = make_wfrag(W_ih1, gateA, cellA, 0, quad, scA);
    float4 Aic1 = make_wfrag(W_ih1, gateA, cellA, 1, quad, scA);
    float4 Ahc0 = make_wfrag(W_hh1, gateA, cellA, 0, quad, scA);
    float4 Ahc1 = make_wfrag(W_hh1, gateA, cellA, 1, quad, scA);
    PIN(A0c0) PIN(A0c1) PIN(Aic0) PIN(Aic1) PIN(Ahc0) PIN(Ahc1)

    // ---- D-cell ownership: reg = gate, cell = 4*wv + quad, batch = col ----
    const int  cellD = 4 * wv + quad;
    const bool ewok  = (cellD < HID);
    const bool grpA  = (wv < 8);          // cells 0..31 = chunk0 producers
    f32x4 bias0, bias1, wx0;
    #pragma unroll
    for (int g = 0; g < 4; ++g) {
        const float s = (g == 2) ? 2.0f * LOG2E : -LOG2E;
        bias0[g] = ewok ? (b_ih0[g * HID + cellD] + b_hh0[g * HID + cellD]) * s : 0.f;
        bias1[g] = ewok ? (b_ih1[g * HID + cellD] + b_hh1[g * HID + cellD]) * s : 0.f;
        wx0[g]   = ewok ? W_ih0[g * HID + cellD] * s : 0.f;   // rank-1 x weights
    }
    // h write-back index in B-layout for (cellD, col). grpA -> offset < 512
    // (chunk0 region); grpB -> >= 512 (chunk1 region).
    const int wi = (cellD >> 5) * 512 + (((cellD & 31) >> 3) * 16 + col) * 8 + (cellD & 7);

    float ct0 = 0.f, ct1 = 0.f;           // c * 2*log2e, both layers
    f32x4 sv0 = {0.f, 0.f, 0.f, 0.f};     // grpB deferred accumulators
    f32x4 sv1 = {0.f, 0.f, 0.f, 0.f};
    __syncthreads();

    // ---- prologue u=0: layer-0 only, h0^0 = 0 => gates = wx0*x_0 + bias0
    {
        const float xr = xs[col];
        f32x4 a;
        #pragma unroll
        for (int g = 0; g < 4; ++g) a[g] = __builtin_fmaf(wx0[g], xr, bias0[g]);
        if (grpA) {
            const float h = cell_update(a, ct0);
            H0[1][wi] = (_Float16)h;      // h0^1 chunk0
        } else {
            sv0 = a;                      // defer (no L1 part yet)
        }
    }
    __syncthreads();                      // bar1(1)

    // ---- peeled u=1 (pu=1, pn=0): B's deferred EW has no h1 yet ----
    {
        const half8 b0c0 = *(const half8*)(&H0[1][lane * 8]);
        const half8 b1c0 = *(const half8*)(&H1[0][lane * 8]);    // zeros
        const float xr   = xs[XST + col];
        f32x4 t;
        #pragma unroll
        for (int g = 0; g < 4; ++g) t[g] = __builtin_fmaf(wx0[g], xr, bias0[g]);
        f32x4 acc0 = MFMA(A0c0, b0c0, t);
        f32x4 acc1 = MFMA(Aic0, b0c0, bias1);
        acc1 = MFMA(Ahc0, b1c0, acc1);
        if (!grpA) {
            const float h = cell_update(sv0, ct0);
            H0[1][wi] = (_Float16)h;      // h0^1 chunk1
        }
        __syncthreads();                  // bar2(1)
        const half8 b0c1 = *(const half8*)(&H0[1][512 + lane * 8]);
        const half8 b1c1 = *(const half8*)(&H1[0][512 + lane * 8]);
        acc0 = MFMA(A0c1, b0c1, acc0);
        acc1 = MFMA(Aic1, b0c1, acc1);
        acc1 = MFMA(Ahc1, b1c1, acc1);
        if (grpA) {
            const float h0n = cell_update(acc0, ct0);
            H0[0][wi] = (_Float16)h0n;    // h0^2 chunk0
            const float h1n = cell_update(acc1, ct1);
            H1[1][wi] = (_Float16)h1n;    // h1^1 chunk0
        } else { sv0 = acc0; sv1 = acc1; }
        __syncthreads();                  // bar1(2)
    }

    // ---- main loop u=2..TT-1 (510 iters, even for unroll 2) ----
    #pragma unroll 2
    for (int u = 2; u < TT; ++u) {
        const int pu = u & 1, pn = pu ^ 1;

        // phase0: chunk0 reads + MFMAs || grpB deferred EW(u-1) + writes
        const half8 b0c0 = *(const half8*)(&H0[pu][lane * 8]);
        const half8 b1c0 = *(const half8*)(&H1[pn][lane * 8]);
        const float xr   = xs[u * XST + col];
        f32x4 t;
        #pragma unroll
        for (int g = 0; g < 4; ++g) t[g] = __builtin_fmaf(wx0[g], xr, bias0[g]);
        f32x4 acc0 = MFMA(A0c0, b0c0, t);
        f32x4 acc1 = MFMA(Aic0, b0c0, bias1);
        acc1 = MFMA(Ahc0, b1c0, acc1);
        if (!grpA) {
            const float h0n = cell_update(sv0, ct0);
            H0[pu][wi] = (_Float16)h0n;   // h0^u chunk1
            const float h1n = cell_update(sv1, ct1);
            H1[pn][wi] = (_Float16)h1n;   // h1^{u-1} chunk1
        }
        __syncthreads();                  // bar2(u): gates chunk1 writes

        // phase1: chunk1 reads + MFMAs || grpA EW(u) + writes
        const half8 b0c1 = *(const half8*)(&H0[pu][512 + lane * 8]);
        const half8 b1c1 = *(const half8*)(&H1[pn][512 + lane * 8]);
        acc0 = MFMA(A0c1, b0c1, acc0);
        acc1 = MFMA(Aic1, b0c1, acc1);
        acc1 = MFMA(Ahc1, b1c1, acc1);
        if (grpA) {
            const float h0n = cell_update(acc0, ct0);
            H0[pn][wi] = (_Float16)h0n;   // h0^{u+1} chunk0
            const float h1n = cell_update(acc1, ct1);
            H1[pu][wi] = (_Float16)h1n;   // h1^u chunk0
        } else { sv0 = acc0; sv1 = acc1; }
        __syncthreads();                  // bar1(u+1): gates chunk0 writes
    }

    // ---- epilogue u=TT (pu=0, pn=1): layer-1 only -> h1^TT into hfin ----
    {
        const half8 b0c0 = *(const half8*)(&H0[0][lane * 8]);        // h0^TT c0
        const half8 b1c0 = *(const half8*)(&H1[1][lane * 8]);        // h1^{TT-1} c0
        f32x4 acc1 = MFMA(Aic0, b0c0, bias1);
        acc1 = MFMA(Ahc0, b1c0, acc1);
        if (!grpA) {
            const float h0n = cell_update(sv0, ct0);
            H0[0][wi] = (_Float16)h0n;    // h0^TT chunk1 (feeds Aic1 below)
            const float h1n = cell_update(sv1, ct1);
            H1[1][wi] = (_Float16)h1n;    // h1^{TT-1} chunk1
        }
        __syncthreads();                  // bar2(TT)
        const half8 b0c1 = *(const half8*)(&H0[0][512 + lane * 8]);
        const half8 b1c1 = *(const half8*)(&H1[1][512 + lane * 8]);
        acc1 = MFMA(Aic1, b0c1, acc1);
        acc1 = MFMA(Ahc1, b1c1, acc1);
        const float h1n = cell_update(acc1, ct1);
        hfin[cellD * NB + col] = h1n;     // cells 50/51 -> unused slots
    }
    __syncthreads();

    // ---------- FC epilogue: out[b] = fc_b + fc_w . h1^(TT)[b,:] ----------
    if (tid < NB) {
        float s = fc_b[0];
        for (int k = 0; k < HID; ++k)
            s += fc_w[k] * hfin[k * NB + tid];
        out[b0 + tid] = s;
    }
}

extern "C" void kernel_launch(void* const* d_in, const int* in_sizes, int n_in,
                              void* d_out, int out_size, void* d_ws, size_t ws_size,
                              hipStream_t stream) {
    (void)in_sizes; (void)n_in; (void)d_ws; (void)ws_size; (void)out_size;
    const float* x     = (const float*)d_in[0];
    const float* W_ih0 = (const float*)d_in[1];
    const float* W_hh0 = (const float*)d_in[2];
    const float* b_ih0 = (const float*)d_in[3];
    const float* b_hh0 = (const float*)d_in[4];
    const float* W_ih1 = (const float*)d_in[5];
    const float* W_hh1 = (const float*)d_in[6];
    const float* b_ih1 = (const float*)d_in[7];
    const float* b_hh1 = (const float*)d_in[8];
    const float* fc_w  = (const float*)d_in[9];
    const float* fc_b  = (const float*)d_in[10];

    dim3 grid(4096 / NB);   // 256 blocks, 1 per CU
    dim3 block(832);        // 13 waves
    lstm2_mfma_kernel<<<grid, block, 0, stream>>>(
        x, W_ih0, W_hh0, b_ih0, b_hh0,
        W_ih1, W_hh1, b_ih1, b_hh1,
        fc_w, fc_b, (float*)d_out);
}

// Round 5
// 404.453 us; speedup vs baseline: 1.0762x; 1.0762x over previous
//
#include <hip/hip_runtime.h>

// LSTMPricePredictor: B=4096, T=512, IN=1, H=50, 2 layers + FC(50->1)
// R21 = R20 resubmit (previous round was an infra failure, no data).
//   Lambda-with-attribute replaced by macro STEP to remove a compile-
//   fragility vector; logic identical.
// R20 theory: R17 (best, 362us) + latency/issue micro-bundle.
//   Post-mortems R18 (7wx2tile, -7%) and R19 (K-split 2-barrier, -12%):
//   both structural overlap attempts regressed. Model: step ~1695cyc =
//   serialized phases (LDS read burst ~620 + MFMA ~100 + EW trans burst
//   ~450 + writes ~150 + barrier/skew ~350); every op is on the recurrence
//   critical path, so extra barriers serialize concurrent EW. Shaves:
//   (1) xs transposed [col][u], float4 read once per 4 steps (was b32/step);
//   (2) acc1 as two 2-deep MFMA chains + vector add (was 4-deep chain);
//   (3) manual 4-step blocks (unroll-4, fewer parity/loop ops).
// Carried from R17: x rank-1 via C-operand, bias as MFMA C-operand,
//   unconditional h stores into dead k=50/51 slots, 2-rcp cell_update
//   with c pre-scaled by 2*log2e, raw v_exp_f32.

typedef _Float16 half8 __attribute__((ext_vector_type(8)));
typedef float    f32x4 __attribute__((ext_vector_type(4)));

#define TT    512
#define HID   50
#define NB    16         // batch rows per block
#define XP    516        // xs row stride (floats): 16B-aligned, 2-way banks
#define LOG2E 1.44269504f

// Weight A-fragment: lane's 8 fp16 for K-chunk `chunk`, pre-scaled by the
// gate's exp2 factor. Row m -> gate = m&3, cell = 4*wv + (m>>2).
// W is (200 x 50): element [gate*50+cell][k]. Rows with cell >= 50 and
// k-slots >= 50 are zero (dead lanes multiply by zero).
__device__ __forceinline__ float4 make_wfrag(const float* W, int gate, int cell,
                                             int chunk, int quad, float scale) {
    half8 hv = {};
    #pragma unroll
    for (int j = 0; j < 8; ++j) {
        const int k = 32 * chunk + 8 * quad + j;
        float v = 0.0f;
        if (cell < HID && k < HID) v = W[(gate * HID + cell) * HID + k] * scale;
        hv[j] = (_Float16)v;
    }
    return __builtin_bit_cast(float4, hv);
}

// Shared-rcp LSTM cell update on pre-scaled gates, RAW hardware exp2.
//   a0 = -i*log2e, a1 = -f*log2e, a2 = 2g*log2e, a3 = -o*log2e.
// ct = c * 2*log2e carried across steps. Common denominator:
//   ct' = [ct*p + K(eg-1)*q] / (p*q),  p=(1+ei)(1+eg), q=(1+ef), K=2log2e.
// Worst-case p*q <= 2^82 -- no overflow. Dead lanes: all-zero gates give
// ei=ef=eg=eo=1 -> ct stays 0, h = 0 exactly.
__device__ __forceinline__ float cell_update(const f32x4 a, float& ct) {
    const float K  = 2.0f * LOG2E;
    const float ei = __builtin_amdgcn_exp2f(a[0]);   // e^{-i}
    const float ef = __builtin_amdgcn_exp2f(a[1]);   // e^{-f}
    const float eg = __builtin_amdgcn_exp2f(a[2]);   // e^{2g}
    const float eo = __builtin_amdgcn_exp2f(a[3]);   // e^{-o}
    const float p  = (1.0f + ei) * (1.0f + eg);
    const float q  = 1.0f + ef;
    const float t1 = __builtin_fmaf(eg, K, -K);                  // K*(eg-1)
    const float num = __builtin_fmaf(ct, p, t1 * q);
    ct = num * __builtin_amdgcn_rcpf(p * q);                     // K*c'
    const float ec = __builtin_amdgcn_exp2f(ct);                 // e^{2c'}
    return (ec - 1.0f) *
        __builtin_amdgcn_rcpf((1.0f + eo) * (ec + 1.0f));        // sig(o)*tanh(c')
}

#define PIN(f) asm volatile("" : "+v"(f.x), "+v"(f.y), "+v"(f.z), "+v"(f.w));
#define MFMA(af, b, c) __builtin_amdgcn_mfma_f32_16x16x32_f16(__builtin_bit_cast(half8, (af)), (b), (c), 0, 0, 0)

// One full step u (pu = u&1): reads h0^u, h1^{u-1}; writes h0^{u+1}, h1^u.
#define STEP(pu, xr) do {                                                   \
    const int pn_ = (pu) ^ 1;                                               \
    const half8 b0c0 = *(const half8*)(&H0[(pu)][lane * 8]);                \
    const half8 b0c1 = *(const half8*)(&H0[(pu)][512 + lane * 8]);          \
    const half8 b1c0 = *(const half8*)(&H1[pn_][lane * 8]);                 \
    const half8 b1c1 = *(const half8*)(&H1[pn_][512 + lane * 8]);           \
    f32x4 t_;                                                               \
    _Pragma("unroll")                                                       \
    for (int g_ = 0; g_ < 4; ++g_)                                          \
        t_[g_] = __builtin_fmaf(wx0[g_], (xr), bias0[g_]);                  \
    f32x4 acc0_ = MFMA(A0c0, b0c0, t_);                                     \
    acc0_ = MFMA(A0c1, b0c1, acc0_);                                        \
    f32x4 p_ = MFMA(Aic0, b0c0, bias1);                                     \
    p_ = MFMA(Ahc0, b1c0, p_);                                              \
    f32x4 q_ = MFMA(Aic1, b0c1, zro);                                       \
    q_ = MFMA(Ahc1, b1c1, q_);                                              \
    const float h0n_ = cell_update(acc0_, ct0);                             \
    H0[pn_][wi] = (_Float16)h0n_;              /* h0^{u+1} */               \
    const f32x4 acc1_ = p_ + q_;                                            \
    const float h1n_ = cell_update(acc1_, ct1);                             \
    H1[(pu)][wi] = (_Float16)h1n_;             /* h1^u */                   \
    __syncthreads();                                                        \
} while (0)

extern "C" __global__ __launch_bounds__(832, 4)
void lstm2_mfma_kernel(const float* __restrict__ x,
                       const float* __restrict__ W_ih0, const float* __restrict__ W_hh0,
                       const float* __restrict__ b_ih0, const float* __restrict__ b_hh0,
                       const float* __restrict__ W_ih1, const float* __restrict__ W_hh1,
                       const float* __restrict__ b_ih1, const float* __restrict__ b_hh1,
                       const float* __restrict__ fc_w, const float* __restrict__ fc_b,
                       float* __restrict__ out)
{
    // h-state in B-fragment layout: element (k, n) at (k>>5)*512 +
    // (((k&31)>>3)*16 + n)*8 + (k&7). k<50 = h; k=50/51 slots are dead
    // (zero A-weights) and absorb the cellD=50/51 stores (h=0 anyway).
    __shared__ _Float16 H0[2][1024];
    __shared__ _Float16 H1[2][1024];
    __shared__ float    xs[NB * XP];      // x staged fp32, [col*XP + u]
    __shared__ float    hfin[52 * NB];    // fp32 h1^(TT) for the FC epilogue

    const int tid  = threadIdx.x;
    const int lane = tid & 63;
    const int wv   = tid >> 6;            // wave 0..12 = gate-row tile
    const int b0   = blockIdx.x * NB;

    for (int i = tid; i < 1024; i += 832) {
        H0[0][i] = (_Float16)0.f; H0[1][i] = (_Float16)0.f;
        H1[0][i] = (_Float16)0.f; H1[1][i] = (_Float16)0.f;
    }
    // One-shot x stage: coalesced global read (consecutive tid = consecutive
    // timesteps of one row), LDS write [row][u].
    for (int i = tid; i < NB * TT; i += 832) {
        const int row = i >> 9;           // batch row 0..15
        const int uu  = i & (TT - 1);     // timestep
        xs[row * XP + uu] = x[(size_t)(b0 + row) * TT + uu];
    }

    const int quad = lane >> 4;
    const int col  = lane & 15;           // batch column
    const int mrow = lane & 15;           // A-row within tile
    const int gateA = mrow & 3;
    const int cellA = 4 * wv + (mrow >> 2);
    const float scA = (gateA == 2) ? 2.0f * LOG2E : -LOG2E;

    // ---- A-fragments (weights, exp2-prescaled), loaded once, pinned ----
    float4 A0c0 = make_wfrag(W_hh0, gateA, cellA, 0, quad, scA);
    float4 A0c1 = make_wfrag(W_hh0, gateA, cellA, 1, quad, scA);
    float4 Aic0 = make_wfrag(W_ih1, gateA, cellA, 0, quad, scA);
    float4 Aic1 = make_wfrag(W_ih1, gateA, cellA, 1, quad, scA);
    float4 Ahc0 = make_wfrag(W_hh1, gateA, cellA, 0, quad, scA);
    float4 Ahc1 = make_wfrag(W_hh1, gateA, cellA, 1, quad, scA);
    PIN(A0c0) PIN(A0c1) PIN(Aic0) PIN(Aic1) PIN(Ahc0) PIN(Ahc1)

    // ---- D-cell ownership: reg = gate, cell = 4*wv + quad, batch = col ----
    const int  cellD = 4 * wv + quad;
    const bool ewok  = (cellD < HID);
    f32x4 bias0, bias1, wx0;
    #pragma unroll
    for (int g = 0; g < 4; ++g) {
        const float s = (g == 2) ? 2.0f * LOG2E : -LOG2E;
        bias0[g] = ewok ? (b_ih0[g * HID + cellD] + b_hh0[g * HID + cellD]) * s : 0.f;
        bias1[g] = ewok ? (b_ih1[g * HID + cellD] + b_hh1[g * HID + cellD]) * s : 0.f;
        wx0[g]   = ewok ? W_ih0[g * HID + cellD] * s : 0.f;   // rank-1 x weights
    }
    // h write-back index in B-layout for (cellD, col); cellD 50/51 land in
    // the dead k=50/51 slots (zero A-weights) -> stores are unconditional.
    const int wi = (cellD >> 5) * 512 + (((cellD & 31) >> 3) * 16 + col) * 8 + (cellD & 7);

    float ct0 = 0.f, ct1 = 0.f;           // c * 2*log2e, both layers
    const f32x4 zro = {0.f, 0.f, 0.f, 0.f};
    __syncthreads();

    // ---- prologue u=0: layer-0 only, h0^0 = 0 => gates = wx0*x_0 + bias0
    float4 xq = *(const float4*)(&xs[col * XP]);     // x_{0..3}
    {
        f32x4 a;
        #pragma unroll
        for (int g = 0; g < 4; ++g) a[g] = __builtin_fmaf(wx0[g], xq.x, bias0[g]);
        const float h = cell_update(a, ct0);
        H0[1][wi] = (_Float16)h;          // h0^1
        __syncthreads();
    }
    // steps u = 1,2,3 from the prologue's float4
    STEP(1, xq.y);
    STEP(0, xq.z);
    STEP(1, xq.w);

    // ---- main loop: 4-step blocks, u = ub..ub+3, ub = 4..508 ----
    for (int ub = 4; ub < TT; ub += 4) {
        xq = *(const float4*)(&xs[col * XP + ub]);
        STEP(0, xq.x);
        STEP(1, xq.y);
        STEP(0, xq.z);
        STEP(1, xq.w);
    }

    // ---- epilogue u=TT (pu=0): layer-1 only -> h1^TT into hfin ----
    {
        const half8 b0c0 = *(const half8*)(&H0[0][lane * 8]);        // h0^TT
        const half8 b0c1 = *(const half8*)(&H0[0][512 + lane * 8]);
        const half8 b1c0 = *(const half8*)(&H1[1][lane * 8]);        // h1^{TT-1}
        const half8 b1c1 = *(const half8*)(&H1[1][512 + lane * 8]);
        f32x4 p = MFMA(Aic0, b0c0, bias1);
        p = MFMA(Ahc0, b1c0, p);
        f32x4 q = MFMA(Aic1, b0c1, zro);
        q = MFMA(Ahc1, b1c1, q);
        const f32x4 acc1 = p + q;
        const float h1n = cell_update(acc1, ct1);
        hfin[cellD * NB + col] = h1n;     // cells 50/51 -> unused slots
    }
    __syncthreads();

    // ---------- FC epilogue: out[b] = fc_b + fc_w . h1^(TT)[b,:] ----------
    if (tid < NB) {
        float s = fc_b[0];
        for (int k = 0; k < HID; ++k)
            s += fc_w[k] * hfin[k * NB + tid];
        out[b0 + tid] = s;
    }
}

extern "C" void kernel_launch(void* const* d_in, const int* in_sizes, int n_in,
                              void* d_out, int out_size, void* d_ws, size_t ws_size,
                              hipStream_t stream) {
    (void)in_sizes; (void)n_in; (void)d_ws; (void)ws_size; (void)out_size;
    const float* x     = (const float*)d_in[0];
    const float* W_ih0 = (const float*)d_in[1];
    const float* W_hh0 = (const float*)d_in[2];
    const float* b_ih0 = (const float*)d_in[3];
    const float* b_hh0 = (const float*)d_in[4];
    const float* W_ih1 = (const float*)d_in[5];
    const float* W_hh1 = (const float*)d_in[6];
    const float* b_ih1 = (const float*)d_in[7];
    const float* b_hh1 = (const float*)d_in[8];
    const float* fc_w  = (const float*)d_in[9];
    const float* fc_b  = (const float*)d_in[10];

    dim3 grid(4096 / NB);   // 256 blocks, 1 per CU
    dim3 block(832);        // 13 waves
    lstm2_mfma_kernel<<<grid, block, 0, stream>>>(
        x, W_ih0, W_hh0, b_ih0, b_hh0,
        W_ih1, W_hh1, b_ih1, b_hh1,
        fc_w, fc_b, (float*)d_out);
}